// Round 8
// baseline (857.540 us; speedup 1.0000x reference)
//
#include <hip/hip_runtime.h>
#include <cstdint>
#include <cstddef>

// ===========================================================================
// FP16 MFMA pipeline (R8).
// R8 changes vs R7 (profile: conv_l1 218us VALUBusy=93% MfmaUtil=6%):
//  (1) conv_l1 im2col: hoisted index math — each thread owns exactly two
//      r5 = e&511 values; (valid, offset) precomputed once, inner loop is
//      16x {LDS read, cvt, LDS store} (~4 ops/elem vs ~20).
//  (2) conv_mfma: 9-tap loop fully unrolled + per-mt base offsets ->
//      tap address math becomes compile-time immediates in ds_read;
//      launch_bounds(256,3) caps VGPRs so load hoisting can't drop occupancy.
// ===========================================================================

typedef _Float16 f16x8 __attribute__((ext_vector_type(8)));
typedef __attribute__((ext_vector_type(4))) float f32x4;

#define WL 36864  // fp16 elems per transformed conv layer: 9 taps * 8 * 512

// ---------------------------------------------------------------------------
// Conv weight transform: cw_rest [5][64][64][3][3] ->
//   wbuf5 [5][tap9][cc2][nt4][64][8] fp16 ; cw1 -> w1buf [nt4][64][8] (K=27 pad 32)
// ---------------------------------------------------------------------------
__global__ __launch_bounds__(256)
void wtransform(const float* __restrict__ cwr, const float* __restrict__ cw1,
                _Float16* __restrict__ wbuf5, _Float16* __restrict__ w1buf) {
  int i = blockIdx.x * 256 + threadIdx.x;
  if (i < 184320) {
    int layer = i / 36864; int rem = i - layer * 36864;
    int tap = rem / 4096;  int r2 = rem - tap * 4096;
    int cc = r2 / 2048;    int r3 = r2 - cc * 2048;
    int nt = r3 / 512;     int r4 = r3 - nt * 512;
    int lane = r4 / 8;     int j = r4 - lane * 8;
    int ic = cc * 32 + (lane >> 4) * 8 + j;
    int oc = nt * 16 + (lane & 15);
    float w = cwr[(((size_t)layer * 64 + oc) * 64 + ic) * 9 + tap];
    wbuf5[(size_t)layer * 36864 + tap * 4096 + (cc * 4 + nt) * 512 + lane * 8 + j] =
        (_Float16)w;
  } else if (i < 184320 + 2048) {
    int e = i - 184320;
    int nt = e / 512; int r4 = e - nt * 512;
    int lane = r4 / 8; int j = r4 - lane * 8;
    int k = (lane >> 4) * 8 + j;
    float w = 0.f;
    if (k < 27) {
      int tap = k / 3, ic = k - tap * 3;
      int oc = nt * 16 + (lane & 15);
      w = cw1[((size_t)oc * 3 + ic) * 9 + tap];
    }
    w1buf[nt * 512 + lane * 8 + j] = (_Float16)w;
  }
}

// ---------------------------------------------------------------------------
// Lin weight transform: W [K,1024] -> frag [K/32][nt64][64][8] fp16.
// ---------------------------------------------------------------------------
__global__ __launch_bounds__(256)
void wtransform_lin(const float* __restrict__ w, _Float16* __restrict__ frag,
                    int KS) {
  int i = blockIdx.x * 256 + threadIdx.x;
  int total = KS * 64 * 512;
  if (i >= total) return;
  int ks = i / (64 * 512); int rem = i - ks * (64 * 512);
  int nt = rem / 512;      int r = rem - nt * 512;
  int lane = r / 8;        int j = r - lane * 8;
  int k = ks * 32 + (lane >> 4) * 8 + j;
  int n = nt * 16 + (lane & 15);
  frag[((size_t)ks * 64 + nt) * 512 + lane * 8 + j] = (_Float16)w[(size_t)k * 1024 + n];
}

// ---------------------------------------------------------------------------
// FP16 MFMA gemm: out[m,n] = sum_k A[m,k] W[k,n] + bias[n]; A fp32 rows.
// 32-col blocks, grid (32, ceil(M/16)) = 288 blocks.
// ---------------------------------------------------------------------------
template<int KTOT>
__global__ __launch_bounds__(256)
void gemm_mfma(const float* __restrict__ A1, const float* __restrict__ A2,
               const _Float16* __restrict__ frag,
               const float* __restrict__ bias, float* __restrict__ out, int M) {
  __shared__ f32x4 s_red[4][2][64];  // 8KB
  const int tid = threadIdx.x;
  const int wave = tid >> 6, lane = tid & 63;
  const int q = lane >> 4, ml = lane & 15;
  const int m0 = blockIdx.y * 16;
  const int nb = blockIdx.x;           // 32-col block
  int row = m0 + ml; if (row >= M) row = M - 1;

  f32x4 acc[2];
#pragma unroll
  for (int nt = 0; nt < 2; ++nt) acc[nt] = (f32x4){0.f, 0.f, 0.f, 0.f};

  constexpr int KSW = KTOT / 128;
  const int ksBase = wave * KSW;
#pragma unroll 2
  for (int s = 0; s < KSW; ++s) {
    int ks = ksBase + s;
    int k0 = ks * 32 + q * 8;
    const float* ap;
    if constexpr (KTOT == 2048) {
      ap = (k0 >= 1024) ? (A2 + (size_t)row * 1024 + (k0 - 1024))
                        : (A1 + (size_t)row * 1024 + k0);
    } else {
      ap = A1 + (size_t)row * 1024 + k0;
    }
    float4 va = *(const float4*)ap;
    float4 vb = *(const float4*)(ap + 4);
    f16x8 av;
    av[0] = (_Float16)va.x; av[1] = (_Float16)va.y;
    av[2] = (_Float16)va.z; av[3] = (_Float16)va.w;
    av[4] = (_Float16)vb.x; av[5] = (_Float16)vb.y;
    av[6] = (_Float16)vb.z; av[7] = (_Float16)vb.w;
    const _Float16* fb = frag + ((size_t)ks * 64 + nb * 2) * 512 + lane * 8;
#pragma unroll
    for (int nt = 0; nt < 2; ++nt) {
      f16x8 bv = *(const f16x8*)(fb + nt * 512);
      acc[nt] = __builtin_amdgcn_mfma_f32_16x16x32_f16(av, bv, acc[nt], 0, 0, 0);
    }
  }
#pragma unroll
  for (int nt = 0; nt < 2; ++nt) s_red[wave][nt][lane] = acc[nt];
  __syncthreads();
  if (wave < 2) {
    int nt = wave;
    f32x4 sum = s_red[0][nt][lane];
#pragma unroll
    for (int w2 = 1; w2 < 4; ++w2) {
      f32x4 p = s_red[w2][nt][lane];
      sum[0] += p[0]; sum[1] += p[1]; sum[2] += p[2]; sum[3] += p[3];
    }
    int n = nb * 32 + nt * 16 + ml;
    float bv = bias[n];
#pragma unroll
    for (int r = 0; r < 4; ++r) {
      int m = m0 + q * 4 + r;
      if (m < M) out[(size_t)m * 1024 + n] = sum[r] + bv;
    }
  }
}

// ---------------------------------------------------------------------------
// conv3x3(SAME)+bias+relu+maxpool2, IC=OC=64, fp16 MFMA implicit GEMM.
// R8: 9-tap loop fully unrolled; per-mt A base offsets precomputed -> tap
// address math folds into compile-time ds_read offsets. Weight prefetch one
// tap ahead. Pooling fully in-register; one barrier per block.
// ---------------------------------------------------------------------------
template<int TCX, int TCY, bool FP32OUT>
__global__ __launch_bounds__(256, 3)
void conv_mfma(const _Float16* __restrict__ act_in,
               void* __restrict__ act_out,
               const _Float16* __restrict__ wbuf,   // [9][cc2][nt4][64][8]
               const float* __restrict__ bias,
               int IH, int IW) {
  constexpr int PX = TCX + 2, PY = TCY + 2;
  constexpr int MT = (TCX * TCY) / 64;
  __shared__ __align__(16) _Float16 s_patch[PY * PX * 72];

  const int tid = threadIdx.x;
  const int wave = tid >> 6, lane = tid & 63;
  const int q = lane >> 4, ml = lane & 15;
  const int x0 = blockIdx.x * TCX, y0 = blockIdx.y * TCY;
  const int img = blockIdx.z;

  // stage patch: 8 x 16B per position, coalesced
  for (int u = tid; u < PY * PX * 8; u += 256) {
    int pos = u >> 3, sub = u & 7;
    int py = pos / PX, px = pos - py * PX;
    int gy = y0 - 1 + py, gx = x0 - 1 + px;
    uint4 v = {0u, 0u, 0u, 0u};
    if ((unsigned)gy < (unsigned)IH && (unsigned)gx < (unsigned)IW)
      v = *(const uint4*)(act_in + (((size_t)img * IH + gy) * IW + gx) * 64 + sub * 8);
    *(uint4*)(s_patch + pos * 72 + sub * 8) = v;
  }

  // prefetch tap 0 weights (both cc chunks, 8 fragments)
  const _Float16* wl = wbuf + lane * 8;
  f16x8 bw[8], bn[8];
#pragma unroll
  for (int f = 0; f < 8; ++f) bw[f] = *(const f16x8*)(wl + f * 512);

  __syncthreads();

  f32x4 acc[MT][4];
#pragma unroll
  for (int mt = 0; mt < MT; ++mt)
#pragma unroll
    for (int nt = 0; nt < 4; ++nt)
      acc[mt][nt] = (f32x4){0.f, 0.f, 0.f, 0.f};

  int abase[MT];
#pragma unroll
  for (int mt = 0; mt < MT; ++mt) {
    int p = (wave * MT + mt) * 16 + ml;
    abase[mt] = ((p / TCX) * PX + (p % TCX)) * 72 + q * 8;
  }

#pragma unroll
  for (int tap = 0; tap < 9; ++tap) {
    if (tap < 8) {
      const _Float16* np = wl + (tap + 1) * 4096;
#pragma unroll
      for (int f = 0; f < 8; ++f) bn[f] = *(const f16x8*)(np + f * 512);
    }
    const int doff = ((tap / 3) * PX + (tap % 3)) * 72;  // compile-time
#pragma unroll
    for (int cc = 0; cc < 2; ++cc) {
#pragma unroll
      for (int mt = 0; mt < MT; ++mt) {
        f16x8 av = *(const f16x8*)(s_patch + abase[mt] + doff + cc * 32);
#pragma unroll
        for (int nt = 0; nt < 4; ++nt)
          acc[mt][nt] = __builtin_amdgcn_mfma_f32_16x16x32_f16(av, bw[cc * 4 + nt],
                                                               acc[mt][nt], 0, 0, 0);
      }
    }
#pragma unroll
    for (int f = 0; f < 8; ++f) bw[f] = bn[f];
  }

  // ---- in-register bias+relu+2x2 maxpool + direct store ----
  const int OH = IH >> 1, OW = IW >> 1;
#pragma unroll
  for (int nt = 0; nt < 4; ++nt) {
    int oc = nt * 16 + ml;
    float bvs = bias[oc];
    if constexpr (TCX == 16) {
#pragma unroll
      for (int mh = 0; mh < MT / 2; ++mh)
#pragma unroll
        for (int rh = 0; rh < 2; ++rh) {
          float a0 = fmaxf(acc[2 * mh][nt][2 * rh] + bvs, 0.f);
          float a1 = fmaxf(acc[2 * mh][nt][2 * rh + 1] + bvs, 0.f);
          float a2 = fmaxf(acc[2 * mh + 1][nt][2 * rh] + bvs, 0.f);
          float a3 = fmaxf(acc[2 * mh + 1][nt][2 * rh + 1] + bvs, 0.f);
          float m = fmaxf(fmaxf(a0, a1), fmaxf(a2, a3));
          int gy = (y0 >> 1) + wave * (MT / 2) + mh;
          int gx = (x0 >> 1) + q * 2 + rh;
          if (FP32OUT)
            ((float*)act_out)[(((size_t)img * 64 + oc) * OH + gy) * OW + gx] = m;
          else
            ((_Float16*)act_out)[(((size_t)img * OH + gy) * OW + gx) * 64 + oc] =
                (_Float16)m;
        }
    } else {  // TCX==8, MT==1: y-pool across q>>1 via shfl_xor(32)
      float m01 = fmaxf(fmaxf(acc[0][nt][0] + bvs, 0.f), fmaxf(acc[0][nt][1] + bvs, 0.f));
      float m23 = fmaxf(fmaxf(acc[0][nt][2] + bvs, 0.f), fmaxf(acc[0][nt][3] + bvs, 0.f));
      float p0 = fmaxf(m01, __shfl_xor(m01, 32));
      float p1 = fmaxf(m23, __shfl_xor(m23, 32));
      if ((lane & 32) == 0) {
        int gy = (y0 >> 1) + wave;
        int gx0 = (x0 >> 1) + (q & 1) * 2;
        if (FP32OUT) {
          float* o = (float*)act_out + (((size_t)img * 64 + oc) * OH + gy) * OW + gx0;
          o[0] = p0; o[1] = p1;
        } else {
          _Float16* o = (_Float16*)act_out;
          o[(((size_t)img * OH + gy) * OW + gx0) * 64 + oc] = (_Float16)p0;
          o[(((size_t)img * OH + gy) * OW + gx0 + 1) * 64 + oc] = (_Float16)p1;
        }
      }
    }
  }
}

// ---------------------------------------------------------------------------
// Layer 1: IC=3, K=27 (pad 32), planar fp32 input. Tile 16x16 -> pooled 8x8.
// R8: im2col index math hoisted — two r5 values per thread, (valid, offset)
// computed once, inner loop = 16x {LDS read, cvt, LDS store}.
// ---------------------------------------------------------------------------
__global__ __launch_bounds__(256, 4)
void conv_l1(const float* __restrict__ in, _Float16* __restrict__ act_out,
             const _Float16* __restrict__ w1buf, const float* __restrict__ bias) {
  __shared__ __align__(16) char smem[20288];
  float* s_raw = (float*)smem;                       // [3][18][18]
  _Float16* s_im = (_Float16*)(smem + 3904);         // [16][64][8]

  const int tid = threadIdx.x;
  const int wave = tid >> 6, lane = tid & 63;
  const int q = lane >> 4, ml = lane & 15;
  const int x0 = blockIdx.x * 16, y0 = blockIdx.y * 16;
  const int img = blockIdx.z;

  for (int i = tid; i < 972; i += 256) {
    int ic = i / 324, rem = i - ic * 324;
    int yy = rem / 18, xx = rem - yy * 18;
    int gy = y0 - 1 + yy, gx = x0 - 1 + xx;
    float v = 0.f;
    if ((unsigned)gy < 256u && (unsigned)gx < 256u)
      v = in[((size_t)img * 3 + ic) * 65536 + gy * 256 + gx];
    s_raw[i] = v;
  }
  __syncthreads();

  // hoisted im2col: e = t*512 + r5; this thread owns r5 = tid and tid+256
#pragma unroll
  for (int half = 0; half < 2; ++half) {
    const int r5 = tid + half * 256;
    const int lidx = r5 >> 3, j = r5 & 7;
    const int m = lidx & 15, qq = lidx >> 4;
    const int k = qq * 8 + j;
    const bool valid = (k < 27);
    const int tap = valid ? (k / 3) : 0;
    const int ic = k - tap * 3;
    const int ddy = tap / 3, ddx = tap - ddy * 3;
    const float* src = s_raw + ic * 324 + ddy * 18 + m + ddx;
    _Float16* dst = s_im + r5;
#pragma unroll
    for (int t = 0; t < 16; ++t) {
      float v = valid ? src[t * 18] : 0.f;
      dst[t * 512] = (_Float16)v;
    }
  }
  __syncthreads();

  f16x8 bv[4];
#pragma unroll
  for (int nt = 0; nt < 4; ++nt)
    bv[nt] = *(const f16x8*)(w1buf + nt * 512 + lane * 8);

  f32x4 acc[4][4];
#pragma unroll
  for (int t4 = 0; t4 < 4; ++t4)
#pragma unroll
    for (int nt = 0; nt < 4; ++nt)
      acc[t4][nt] = (f32x4){0.f, 0.f, 0.f, 0.f};

#pragma unroll
  for (int t4 = 0; t4 < 4; ++t4) {
    int t = wave * 4 + t4;
    f16x8 av = *(const f16x8*)(s_im + t * 512 + lane * 8);
#pragma unroll
    for (int nt = 0; nt < 4; ++nt)
      acc[t4][nt] = __builtin_amdgcn_mfma_f32_16x16x32_f16(av, bv[nt], acc[t4][nt], 0, 0, 0);
  }

#pragma unroll
  for (int nt = 0; nt < 4; ++nt) {
    int oc = nt * 16 + ml;
    float bvs = bias[oc];
#pragma unroll
    for (int mh = 0; mh < 2; ++mh)
#pragma unroll
      for (int rh = 0; rh < 2; ++rh) {
        float a0 = fmaxf(acc[2 * mh][nt][2 * rh] + bvs, 0.f);
        float a1 = fmaxf(acc[2 * mh][nt][2 * rh + 1] + bvs, 0.f);
        float a2 = fmaxf(acc[2 * mh + 1][nt][2 * rh] + bvs, 0.f);
        float a3 = fmaxf(acc[2 * mh + 1][nt][2 * rh + 1] + bvs, 0.f);
        float m = fmaxf(fmaxf(a0, a1), fmaxf(a2, a3));
        int gy = blockIdx.y * 8 + wave * 2 + mh;
        int gx = blockIdx.x * 8 + q * 2 + rh;
        act_out[(((size_t)img * 128 + gy) * 128 + gx) * 64 + oc] = (_Float16)m;
      }
  }
}

// ---------------------------------------------------------------------------
// Graph aggregation (two-phase) + metric head (unchanged).
// ---------------------------------------------------------------------------
__global__ __launch_bounds__(256)
void edge_agg_mul(const float* __restrict__ h, const int* __restrict__ ei,
                  int E, float* __restrict__ out) {
  __shared__ int list[1024];
  __shared__ int cnt;
  const int n = blockIdx.x;
  const int tid = threadIdx.x;
  if (tid == 0) cnt = 0;
  __syncthreads();
  for (int e = tid; e < E; e += 256) {
    if (ei[E + e] == n) {
      int p = atomicAdd(&cnt, 1);
      list[p] = ei[e];
    }
  }
  __syncthreads();
  const int c = cnt;
  float ax = 0.f, ay = 0.f, az = 0.f, aw = 0.f;
#pragma unroll 4
  for (int i = 0; i < c; ++i) {
    const float4 v = ((const float4*)(h + (size_t)list[i] * 1024))[tid];
    ax += v.x; ay += v.y; az += v.z; aw += v.w;
  }
  float inv = 1.f / (float)(c > 0 ? c : 1);
  const float4 hv = ((const float4*)(h + (size_t)n * 1024))[tid];
  float4 o;
  o.x = ax * inv * hv.x; o.y = ay * inv * hv.y;
  o.z = az * inv * hv.z; o.w = aw * inv * hv.w;
  ((float4*)(out + (size_t)n * 1024))[tid] = o;
}

__global__ __launch_bounds__(256)
void rbf_pairs(const float* __restrict__ sx, const float* __restrict__ qx,
               const float* __restrict__ center, float* __restrict__ bpre) {
  int gid = blockIdx.x * 256 + threadIdx.x;
  int wid = gid >> 6;
  int lane = gid & 63;
  if (wid >= 23 * 115) return;
  int qq = wid / 115, s = wid - qq * 115;
  const float* sr = sx + (size_t)s * 1024;
  const float* qr = qx + (size_t)qq * 1024;
  const float* cr = center + (size_t)(s / 5) * 1024;
  float S1 = 0.f, S2 = 0.f, S3 = 0.f;
  for (int d = lane; d < 1024; d += 64) {
    float sv = sr[d], qv = qr[d];
    float df = sv - qv;
    float a = expf(-df * df);
    S1 += a;
    S2 += expf(a);
    float sc = 0.25f * cr[d] + 0.5f * sv;
    float d2 = sc - qv;
    S3 += expf(-d2 * d2);
  }
#pragma unroll
  for (int o = 32; o > 0; o >>= 1) {
    S1 += __shfl_down(S1, o);
    S2 += __shfl_down(S2, o);
    S3 += __shfl_down(S3, o);
  }
  if (lane == 0) bpre[wid] = S3 + S1 - 1024.f * logf(S2);
}

__global__ __launch_bounds__(256)
void center_new_k(const float* __restrict__ sx, const float* __restrict__ center,
                  const int* __restrict__ sy, float* __restrict__ out) {
  __shared__ int syv[115];
  int tid = threadIdx.x;
  if (tid < 115) syv[tid] = sy[tid];
  __syncthreads();
  int c = blockIdx.x;
  int d = blockIdx.y * 256 + tid;
  float sum = 0.f; int cnt = 0;
  for (int s = 0; s < 115; ++s)
    if (syv[s] == c) { sum += sx[(size_t)s * 1024 + d]; ++cnt; }
  out[2 + (size_t)c * 1024 + d] =
      0.5f * (sum / (float)(cnt > 0 ? cnt : 1)) + 0.25f * center[(size_t)c * 1024 + d];
}

__global__ __launch_bounds__(256)
void finalize_k(const float* __restrict__ bpre, const int* __restrict__ sy,
                const int* __restrict__ qy, float* __restrict__ out) {
  __shared__ float bls[23][115];
  __shared__ float dis[23][23];
  __shared__ int   syv[115];
  __shared__ float ccnt[23];
  __shared__ float lossq[23];
  __shared__ float accq[23];
  const int tid = threadIdx.x;
  if (tid < 115) syv[tid] = sy[tid];
  __syncthreads();
  if (tid < 23) {
    float mx = -3.4e38f;
    for (int s = 0; s < 115; ++s) mx = fmaxf(mx, bpre[tid * 115 + s]);
    float se = 0.f;
    for (int s = 0; s < 115; ++s) se += expf(bpre[tid * 115 + s] - mx);
    float lse = mx + logf(se);
    for (int s = 0; s < 115; ++s) bls[tid][s] = bpre[tid * 115 + s] - lse;
    int c = 0;
    for (int s = 0; s < 115; ++s) c += (syv[s] == tid);
    ccnt[tid] = (float)(c > 0 ? c : 1);
  }
  __syncthreads();
  for (int i = tid; i < 23 * 23; i += 256) {
    int qq = i / 23, c = i - qq * 23;
    float sum = 0.f;
    for (int s = 0; s < 115; ++s)
      if (syv[s] == c) sum += bls[qq][s];
    dis[qq][c] = sum / ccnt[c];
  }
  __syncthreads();
  if (tid < 23) {
    int qq = tid;
    float mx = -3.4e38f; int am = 0;
    for (int c = 0; c < 23; ++c) {
      float v = dis[qq][c];
      if (v > mx) { mx = v; am = c; }
    }
    float se = 0.f;
    for (int c = 0; c < 23; ++c) se += expf(dis[qq][c] - mx);
    float lse = mx + logf(se);
    int y = qy[qq];
    lossq[qq] = -(dis[qq][y] - lse);
    accq[qq] = (am == y) ? 1.f : 0.f;
  }
  __syncthreads();
  if (tid == 0) {
    float L = 0.f, A = 0.f;
    for (int qq = 0; qq < 23; ++qq) { L += lossq[qq]; A += accq[qq]; }
    out[0] = L;
    out[1] = A;
  }
}

// ---------------------------------------------------------------------------
extern "C" void kernel_launch(void* const* d_in, const int* in_sizes, int n_in,
                              void* d_out, int out_size, void* d_ws, size_t ws_size,
                              hipStream_t stream) {
  const float* sup_x  = (const float*)d_in[0];
  const int*   sup_ei = (const int*)d_in[1];
  const int*   sup_y  = (const int*)d_in[3];
  const float* q_x    = (const float*)d_in[4];
  const int*   q_ei   = (const int*)d_in[5];
  const int*   q_y    = (const int*)d_in[7];
  const float* center = (const float*)d_in[8];
  const float* cw1    = (const float*)d_in[9];
  const float* cb1    = (const float*)d_in[10];
  const float* cwr    = (const float*)d_in[11];
  const float* cbr    = (const float*)d_in[12];
  const float* l2w    = (const float*)d_in[13];
  const float* l2b    = (const float*)d_in[14];
  const float* mw     = (const float*)d_in[15];
  const float* mb     = (const float*)d_in[16];
  float* out = (float*)d_out;

  // ---- workspace carve-up (bytes, 256-aligned) ----
  char* base = (char*)d_ws;
  size_t off = 0;
  auto alloc = [&](size_t n) { char* p = base + off; off += (n + 255) & ~(size_t)255; return p; };
  _Float16* wbuf5 = (_Float16*)alloc(5 * WL * 2);
  _Float16* w1buf = (_Float16*)alloc(2048 * 2);
  float* h1   = (float*)alloc(138 * 1024 * 4);
  float* sxb  = (float*)alloc(138 * 1024 * 4);
  float* h2p  = (float*)alloc(138 * 1024 * 4);
  float* h2   = (float*)alloc(138 * 1024 * 4);
  float* feat = (float*)alloc(138 * 1024 * 4);
  float* bpre = (float*)alloc(23 * 115 * 4);

  const size_t R1_FULL = 138ull * 64 * 64 * 64 * 2;    //  72,351,744 (L2 out, all)
  const size_t R0_FULL = 115ull * 128 * 128 * 64 * 2;  // 241,172,480 (L1 out, 115)
  const size_t R0_23   = 23ull * 128 * 128 * 64 * 2;   //  48,234,496
  const size_t R1_SML  = 12ull * 64 * 64 * 64 * 2;
  const size_t R0_SML  = 12ull * 128 * 128 * 64 * 2;

  const int tier = (ws_size >= off + R1_FULL + R0_FULL + 4096) ? 0
                 : (ws_size >= off + R1_FULL + R0_23 + 4096)   ? 1 : 2;

  _Float16* region1 = (_Float16*)alloc(tier <= 1 ? R1_FULL : R1_SML);
  _Float16* region0 = (_Float16*)alloc(tier == 0 ? R0_FULL : (tier == 1 ? R0_23 : R0_SML));
  _Float16* l3out = region0;
  _Float16* l4out = region0 + (tier <= 1 ? 9043968u : 786432u);
  _Float16* l5out = region0 + (tier <= 1 ? 11304960u : 983040u);
  _Float16* wlin2 = region0;               // overlays, dead after conv chain
  _Float16* wmlp  = region0 + 1048576u;

  wtransform<<<728, 256, 0, stream>>>(cwr, cw1, wbuf5, w1buf);

  if (tier == 0) {
    conv_l1<<<dim3(16, 16, 115), 256, 0, stream>>>(sup_x, region0, w1buf, cb1);
    conv_mfma<16, 16, false><<<dim3(8, 8, 115), 256, 0, stream>>>(
        region0, region1, wbuf5, cbr, 128, 128);
    conv_l1<<<dim3(16, 16, 23), 256, 0, stream>>>(q_x, region0, w1buf, cb1);
    conv_mfma<16, 16, false><<<dim3(8, 8, 23), 256, 0, stream>>>(
        region0, region1 + 115ull * 64 * 64 * 64, wbuf5, cbr, 128, 128);
    conv_mfma<16, 16, false><<<dim3(4, 4, 138), 256, 0, stream>>>(
        region1, l3out, wbuf5 + 1 * WL, cbr + 64, 64, 64);
    conv_mfma<16, 16, false><<<dim3(2, 2, 138), 256, 0, stream>>>(
        l3out, l4out, wbuf5 + 2 * WL, cbr + 128, 32, 32);
    conv_mfma<16, 16, false><<<dim3(1, 1, 138), 256, 0, stream>>>(
        l4out, l5out, wbuf5 + 3 * WL, cbr + 192, 16, 16);
    conv_mfma<8, 8, true><<<dim3(1, 1, 138), 256, 0, stream>>>(
        l5out, h1, wbuf5 + 4 * WL, cbr + 256, 8, 8);
  } else if (tier == 1) {
    for (int c = 0; c < 6; ++c) {
      const float* xin = (c < 5) ? (sup_x + (size_t)c * 23 * 3 * 65536) : q_x;
      conv_l1<<<dim3(16, 16, 23), 256, 0, stream>>>(xin, region0, w1buf, cb1);
      conv_mfma<16, 16, false><<<dim3(8, 8, 23), 256, 0, stream>>>(
          region0, region1 + (size_t)c * 23 * 64 * 64 * 64, wbuf5, cbr, 128, 128);
    }
    conv_mfma<16, 16, false><<<dim3(4, 4, 138), 256, 0, stream>>>(
        region1, l3out, wbuf5 + 1 * WL, cbr + 64, 64, 64);
    conv_mfma<16, 16, false><<<dim3(2, 2, 138), 256, 0, stream>>>(
        l3out, l4out, wbuf5 + 2 * WL, cbr + 128, 32, 32);
    conv_mfma<16, 16, false><<<dim3(1, 1, 138), 256, 0, stream>>>(
        l4out, l5out, wbuf5 + 3 * WL, cbr + 192, 16, 16);
    conv_mfma<8, 8, true><<<dim3(1, 1, 138), 256, 0, stream>>>(
        l5out, h1, wbuf5 + 4 * WL, cbr + 256, 8, 8);
  } else {
    auto run_chain = [&](const float* xin, int n, int gb) {
      conv_l1<<<dim3(16, 16, n), 256, 0, stream>>>(xin, region0, w1buf, cb1);
      conv_mfma<16, 16, false><<<dim3(8, 8, n), 256, 0, stream>>>(
          region0, region1, wbuf5, cbr, 128, 128);
      conv_mfma<16, 16, false><<<dim3(4, 4, n), 256, 0, stream>>>(
          region1, l3out, wbuf5 + 1 * WL, cbr + 64, 64, 64);
      conv_mfma<16, 16, false><<<dim3(2, 2, n), 256, 0, stream>>>(
          l3out, l4out, wbuf5 + 2 * WL, cbr + 128, 32, 32);
      conv_mfma<16, 16, false><<<dim3(1, 1, n), 256, 0, stream>>>(
          l4out, l5out, wbuf5 + 3 * WL, cbr + 192, 16, 16);
      conv_mfma<8, 8, true><<<dim3(1, 1, n), 256, 0, stream>>>(
          l5out, h1 + (size_t)gb * 1024, wbuf5 + 4 * WL, cbr + 256, 8, 8);
    };
    for (int i0 = 0; i0 < 115; i0 += 12)
      run_chain(sup_x + (size_t)i0 * 3 * 65536, (115 - i0 < 12) ? 115 - i0 : 12, i0);
    for (int i0 = 0; i0 < 23; i0 += 12)
      run_chain(q_x + (size_t)i0 * 3 * 65536, (23 - i0 < 12) ? 23 - i0 : 12, 115 + i0);
  }

  // ---- lin weight fragments (region0 now dead) ----
  wtransform_lin<<<4096, 256, 0, stream>>>(l2w, wlin2, 32);
  wtransform_lin<<<8192, 256, 0, stream>>>(mw, wmlp, 64);

  // ---- graph layers (support rows 0..114, query rows 115..137) ----
  edge_agg_mul<<<115, 256, 0, stream>>>(h1, sup_ei, 4096, sxb);
  edge_agg_mul<<<23, 256, 0, stream>>>(h1 + 115 * 1024, q_ei, 1024, sxb + 115 * 1024);
  gemm_mfma<1024><<<dim3(32, 9), 256, 0, stream>>>(sxb, nullptr, wlin2, l2b, h2p, 138);
  edge_agg_mul<<<115, 256, 0, stream>>>(h2p, sup_ei, 4096, h2);
  edge_agg_mul<<<23, 256, 0, stream>>>(h2p + 115 * 1024, q_ei, 1024, h2 + 115 * 1024);
  gemm_mfma<2048><<<dim3(32, 9), 256, 0, stream>>>(h1, h2, wmlp, mb, feat, 138);

  // ---- metric head ----
  rbf_pairs<<<(23 * 115 * 64 + 255) / 256, 256, 0, stream>>>(
      feat, feat + 115 * 1024, center, bpre);
  center_new_k<<<dim3(23, 4), 256, 0, stream>>>(feat, center, sup_y, out);
  finalize_k<<<1, 256, 0, stream>>>(bpre, sup_y, q_y, out);
}